// Round 1
// 680.577 us; speedup vs baseline: 1.0063x; 1.0063x over previous
//
#include <hip/hip_runtime.h>
#include <math.h>

// Problem: B=1048576 rows x C=128 classes, fp32 logits, int targets.
// out = mean(logsumexp(x) - x_t)  +  0.5 * mean_{t==1 & argmax==0}( -log1p(-1/s) )
// where s = sum exp(x - m); when argmax==0, p0 = 1/s exactly.
#define CLS 128
#define PEN_WEIGHT 0.5f
#define ROWS_PER_BLOCK 256
#define NIT 16

// 16 lanes per row, TWO float4 per lane (cols gl*4 and 64+gl*4) = all 128 cols.
// Wave handles 4 rows/iter; 256-thread block = 16 rows/iter, 256 rows total.
// v2: distance-2 software pipeline (a/b buffers) so 4-6 dwordx4 loads stay in
// flight per wave; #pragma unroll 1 keeps VGPRs lean; launch_bounds(256,4)
// guarantees >=4 waves/SIMD. Ballot removed (pred0 only needed on gl==0 lane).
__global__ __launch_bounds__(256, 4) void penalize_loss_main(
        const float* __restrict__ predicts,
        const int*   __restrict__ targets,
        float* __restrict__ ws, int B, int nb) {
    const int tid  = threadIdx.x;
    const int lane = tid & 63;
    const int wave = tid >> 6;        // 0..3
    const int gl   = lane & 15;       // lane within 16-lane row group
    const int sub  = lane >> 4;       // row within the wave's 4-row group

    float acc_ce = 0.0f, acc_pen = 0.0f, acc_cnt = 0.0f;

    const int r_block = blockIdx.x * ROWS_PER_BLOCK;
    const int r0 = r_block + wave * 4 + sub;   // row for iter 0; iter i adds i*16

    auto compute = [&](const float4 v1, const float4 v2, const int t) {
        // row max over 128 elements (8 local + 4-step butterfly in group)
        float lm = fmaxf(fmaxf(fmaxf(v1.x, v1.y), fmaxf(v1.z, v1.w)),
                         fmaxf(fmaxf(v2.x, v2.y), fmaxf(v2.z, v2.w)));
        lm = fmaxf(lm, __shfl_xor(lm, 1, 64));
        lm = fmaxf(lm, __shfl_xor(lm, 2, 64));
        lm = fmaxf(lm, __shfl_xor(lm, 4, 64));
        lm = fmaxf(lm, __shfl_xor(lm, 8, 64));

        // row sum of exp(x - m)
        float e = __expf(v1.x - lm) + __expf(v1.y - lm)
                + __expf(v1.z - lm) + __expf(v1.w - lm)
                + __expf(v2.x - lm) + __expf(v2.y - lm)
                + __expf(v2.z - lm) + __expf(v2.w - lm);
        e += __shfl_xor(e, 1, 64);
        e += __shfl_xor(e, 2, 64);
        e += __shfl_xor(e, 4, 64);
        e += __shfl_xor(e, 8, 64);
        // e == s (uniform within the 16-lane group)

        if (gl == 0) {
            acc_ce += lm + __logf(e);           // logsumexp
            // pred==0 <=> x[0]==rowmax (ties break to index 0); this lane
            // holds x[0] in v1.x, so no ballot needed.
            if (t == 1 && v1.x == lm) {
                acc_pen += -log1pf(-1.0f / e);  // argmax==0 => p0 = 1/s exactly
                acc_cnt += 1.0f;
            }
        }
        // lane holding x_t subtracts it (no shuffle gather needed)
        if (gl == ((t >> 2) & 15)) {
            const int j = t & 3;
            float xt;
            if (t & 64) xt = (j == 0) ? v2.x : (j == 1) ? v2.y : (j == 2) ? v2.z : v2.w;
            else        xt = (j == 0) ? v1.x : (j == 1) ? v1.y : (j == 2) ? v1.z : v1.w;
            acc_ce -= xt;
        }
    };

    if (r_block + ROWS_PER_BLOCK <= B) {
        // Fast path (always taken for B = 4096*256): pipelined, no guards.
        const float* base = predicts + (size_t)r0 * CLS + gl * 4;

        float4 a1 = *(const float4*)(base);
        float4 a2 = *(const float4*)(base + 64);
        int    at = targets[r0];
        float4 b1 = *(const float4*)(base + 16 * CLS);
        float4 b2 = *(const float4*)(base + 16 * CLS + 64);
        int    bt = targets[r0 + 16];

        #pragma unroll 1
        for (int i = 0; i < NIT - 2; i += 2) {
            // compute row-group i while prefetching i+2
            const float4 c1 = a1, c2 = a2; const int ct = at;
            const float* pa = base + (size_t)(i + 2) * 16 * CLS;
            a1 = *(const float4*)(pa);
            a2 = *(const float4*)(pa + 64);
            at = targets[r0 + (i + 2) * 16];
            compute(c1, c2, ct);

            // compute row-group i+1 while prefetching i+3 (i<=12 -> i+3<=15 valid)
            const float4 d1 = b1, d2 = b2; const int dt = bt;
            const float* pb = base + (size_t)(i + 3) * 16 * CLS;
            b1 = *(const float4*)(pb);
            b2 = *(const float4*)(pb + 64);
            bt = targets[r0 + (i + 3) * 16];
            compute(d1, d2, dt);
        }
        compute(a1, a2, at);   // row-group 14
        compute(b1, b2, bt);   // row-group 15
    } else {
        // Guarded tail path (unused when B % ROWS_PER_BLOCK == 0).
        for (int i = 0; i < NIT; ++i) {
            const int r = r0 + i * 16;
            if (r < B) {
                const float* row = predicts + (size_t)r * CLS;
                const float4 v1 = *(const float4*)(row + gl * 4);
                const float4 v2 = *(const float4*)(row + 64 + gl * 4);
                compute(v1, v2, targets[r]);
            }
        }
    }

    // full-wave butterfly sum (64 lanes)
    for (int mask = 1; mask < 64; mask <<= 1) {
        acc_ce  += __shfl_xor(acc_ce,  mask, 64);
        acc_pen += __shfl_xor(acc_pen, mask, 64);
        acc_cnt += __shfl_xor(acc_cnt, mask, 64);
    }

    __shared__ float s_ce[4], s_pen[4], s_cnt[4];
    if (lane == 0) { s_ce[wave] = acc_ce; s_pen[wave] = acc_pen; s_cnt[wave] = acc_cnt; }
    __syncthreads();
    if (tid == 0) {
        ws[blockIdx.x]          = s_ce[0]  + s_ce[1]  + s_ce[2]  + s_ce[3];
        ws[nb + blockIdx.x]     = s_pen[0] + s_pen[1] + s_pen[2] + s_pen[3];
        ws[2 * nb + blockIdx.x] = s_cnt[0] + s_cnt[1] + s_cnt[2] + s_cnt[3];
    }
}

// One block reduces the 3*nb partials and writes the scalar.
__global__ __launch_bounds__(256) void finalize_kernel(
        const float* __restrict__ ws, float* __restrict__ out, int B, int nb) {
    const int tid  = threadIdx.x;
    const int lane = tid & 63;
    const int wave = tid >> 6;

    float ce = 0.0f, pen = 0.0f, cnt = 0.0f;
    for (int i = tid; i < nb; i += 256) {
        ce  += ws[i];
        pen += ws[nb + i];
        cnt += ws[2 * nb + i];
    }
    for (int mask = 1; mask < 64; mask <<= 1) {
        ce  += __shfl_xor(ce,  mask, 64);
        pen += __shfl_xor(pen, mask, 64);
        cnt += __shfl_xor(cnt, mask, 64);
    }
    __shared__ float s_ce[4], s_pen[4], s_cnt[4];
    if (lane == 0) { s_ce[wave] = ce; s_pen[wave] = pen; s_cnt[wave] = cnt; }
    __syncthreads();
    if (tid == 0) {
        const float tce  = s_ce[0]  + s_ce[1]  + s_ce[2]  + s_ce[3];
        const float tpen = s_pen[0] + s_pen[1] + s_pen[2] + s_pen[3];
        const float tcnt = s_cnt[0] + s_cnt[1] + s_cnt[2] + s_cnt[3];
        const float mean_ce  = tce / (float)B;
        const float mean_pen = (tcnt > 0.0f) ? (tpen / tcnt) : 0.0f;
        out[0] = mean_ce + PEN_WEIGHT * mean_pen;
    }
}

extern "C" void kernel_launch(void* const* d_in, const int* in_sizes, int n_in,
                              void* d_out, int out_size, void* d_ws, size_t ws_size,
                              hipStream_t stream) {
    const float* predicts = (const float*)d_in[0];
    const int*   targets  = (const int*)d_in[1];
    const int B = in_sizes[1];                    // 1048576
    float* ws  = (float*)d_ws;
    float* out = (float*)d_out;

    const int nb = (B + ROWS_PER_BLOCK - 1) / ROWS_PER_BLOCK;   // 4096
    penalize_loss_main<<<nb, 256, 0, stream>>>(predicts, targets, ws, B, nb);
    finalize_kernel<<<1, 256, 0, stream>>>(ws, out, B, nb);
}

// Round 2
// 653.264 us; speedup vs baseline: 1.0483x; 1.0418x over previous
//
#include <hip/hip_runtime.h>
#include <math.h>

// Problem: B=1048576 rows x C=128 classes, fp32 logits, int targets.
// out = mean(logsumexp(x) - x_t)  +  0.5 * mean_{t==1 & argmax==0}( -log1p(-1/s) )
// where s = sum exp(x - m); when argmax==0, p0 = 1/s exactly.
#define CLS 128
#define PEN_WEIGHT 0.5f
#define ROWS_PER_BLOCK 256
#define NIT 16

typedef float v4f __attribute__((ext_vector_type(4)));

// 16 lanes per row, TWO float4 per lane (cols gl*4 and 64+gl*4) = all 128 cols.
// Wave handles 4 rows/iter; 256-thread block = 16 rows/iter, 256 rows total.
// v3: distance-3 rotating prefetch (A/B/C buffers -> ~6 KiB in flight per wave),
// nontemporal dwordx4 loads (pure stream, zero reuse), rolled loop, no
// min-wave clamp (avoid any spill pathology). Math identical to v1 (two-pass
// max then sum) so the result stays bit-identical.
__global__ __launch_bounds__(256) void penalize_loss_main(
        const float* __restrict__ predicts,
        const int*   __restrict__ targets,
        float* __restrict__ ws, int B, int nb) {
    const int tid  = threadIdx.x;
    const int lane = tid & 63;
    const int wave = tid >> 6;        // 0..3
    const int gl   = lane & 15;       // lane within 16-lane row group
    const int sub  = lane >> 4;       // row within the wave's 4-row group

    float acc_ce = 0.0f, acc_pen = 0.0f, acc_cnt = 0.0f;

    const int r_block = blockIdx.x * ROWS_PER_BLOCK;
    const int r0 = r_block + wave * 4 + sub;   // row for iter 0; iter i adds i*16

    auto compute = [&](const v4f v1, const v4f v2, const int t) {
        // row max over 128 elements (8 local + 4-step butterfly in group)
        float lm = fmaxf(fmaxf(fmaxf(v1.x, v1.y), fmaxf(v1.z, v1.w)),
                         fmaxf(fmaxf(v2.x, v2.y), fmaxf(v2.z, v2.w)));
        lm = fmaxf(lm, __shfl_xor(lm, 1, 64));
        lm = fmaxf(lm, __shfl_xor(lm, 2, 64));
        lm = fmaxf(lm, __shfl_xor(lm, 4, 64));
        lm = fmaxf(lm, __shfl_xor(lm, 8, 64));

        // row sum of exp(x - m)
        float e = __expf(v1.x - lm) + __expf(v1.y - lm)
                + __expf(v1.z - lm) + __expf(v1.w - lm)
                + __expf(v2.x - lm) + __expf(v2.y - lm)
                + __expf(v2.z - lm) + __expf(v2.w - lm);
        e += __shfl_xor(e, 1, 64);
        e += __shfl_xor(e, 2, 64);
        e += __shfl_xor(e, 4, 64);
        e += __shfl_xor(e, 8, 64);
        // e == s (uniform within the 16-lane group)

        if (gl == 0) {
            acc_ce += lm + __logf(e);           // logsumexp
            // pred==0 <=> x[0]==rowmax (ties break to index 0); this lane
            // holds x[0] in v1.x, so no ballot needed.
            if (t == 1 && v1.x == lm) {
                acc_pen += -log1pf(-1.0f / e);  // argmax==0 => p0 = 1/s exactly
                acc_cnt += 1.0f;
            }
        }
        // lane holding x_t subtracts it (no shuffle gather needed)
        if (gl == ((t >> 2) & 15)) {
            const int j = t & 3;
            float xt;
            if (t & 64) xt = (j == 0) ? v2.x : (j == 1) ? v2.y : (j == 2) ? v2.z : v2.w;
            else        xt = (j == 0) ? v1.x : (j == 1) ? v1.y : (j == 2) ? v1.z : v1.w;
            acc_ce -= xt;
        }
    };

    if (r_block + ROWS_PER_BLOCK <= B) {
        // Fast path (always taken for B = 4096*256): distance-3 pipeline.
        const float* base = predicts + (size_t)r0 * CLS + gl * 4;

#define LOADRG(V1, V2, T, idx) do {                                   \
            const float* _p = base + (size_t)(idx) * (16 * CLS);      \
            V1 = __builtin_nontemporal_load((const v4f*)_p);          \
            V2 = __builtin_nontemporal_load((const v4f*)(_p + 64));   \
            T  = targets[r0 + (idx) * 16];                            \
        } while (0)

        v4f A1, A2, B1, B2, C1, C2;
        int At, Bt, Ct;
        LOADRG(A1, A2, At, 0);
        LOADRG(B1, B2, Bt, 1);
        LOADRG(C1, C2, Ct, 2);

        #pragma unroll 1
        for (int i = 0; i < NIT - 1; i += 3) {   // i = 0,3,6,9,12 -> computes 0..14
            const int pa = (i + 3 < NIT) ? i + 3 : NIT - 1;
            const int pb = (i + 4 < NIT) ? i + 4 : NIT - 1;
            const int pc = (i + 5 < NIT) ? i + 5 : NIT - 1;

            v4f t1 = A1, t2 = A2; int tt = At;
            LOADRG(A1, A2, At, pa);
            compute(t1, t2, tt);

            t1 = B1; t2 = B2; tt = Bt;
            LOADRG(B1, B2, Bt, pb);
            compute(t1, t2, tt);

            t1 = C1; t2 = C2; tt = Ct;
            LOADRG(C1, C2, Ct, pc);
            compute(t1, t2, tt);
        }
        compute(A1, A2, At);   // row-group 15
#undef LOADRG
    } else {
        // Guarded tail path (unused when B % ROWS_PER_BLOCK == 0).
        for (int i = 0; i < NIT; ++i) {
            const int r = r0 + i * 16;
            if (r < B) {
                const float* row = predicts + (size_t)r * CLS;
                const v4f v1 = *(const v4f*)(row + gl * 4);
                const v4f v2 = *(const v4f*)(row + 64 + gl * 4);
                compute(v1, v2, targets[r]);
            }
        }
    }

    // full-wave butterfly sum (64 lanes)
    for (int mask = 1; mask < 64; mask <<= 1) {
        acc_ce  += __shfl_xor(acc_ce,  mask, 64);
        acc_pen += __shfl_xor(acc_pen, mask, 64);
        acc_cnt += __shfl_xor(acc_cnt, mask, 64);
    }

    __shared__ float s_ce[4], s_pen[4], s_cnt[4];
    if (lane == 0) { s_ce[wave] = acc_ce; s_pen[wave] = acc_pen; s_cnt[wave] = acc_cnt; }
    __syncthreads();
    if (tid == 0) {
        ws[blockIdx.x]          = s_ce[0]  + s_ce[1]  + s_ce[2]  + s_ce[3];
        ws[nb + blockIdx.x]     = s_pen[0] + s_pen[1] + s_pen[2] + s_pen[3];
        ws[2 * nb + blockIdx.x] = s_cnt[0] + s_cnt[1] + s_cnt[2] + s_cnt[3];
    }
}

// One block reduces the 3*nb partials and writes the scalar.
__global__ __launch_bounds__(256) void finalize_kernel(
        const float* __restrict__ ws, float* __restrict__ out, int B, int nb) {
    const int tid  = threadIdx.x;
    const int lane = tid & 63;
    const int wave = tid >> 6;

    float ce = 0.0f, pen = 0.0f, cnt = 0.0f;
    for (int i = tid; i < nb; i += 256) {
        ce  += ws[i];
        pen += ws[nb + i];
        cnt += ws[2 * nb + i];
    }
    for (int mask = 1; mask < 64; mask <<= 1) {
        ce  += __shfl_xor(ce,  mask, 64);
        pen += __shfl_xor(pen, mask, 64);
        cnt += __shfl_xor(cnt, mask, 64);
    }
    __shared__ float s_ce[4], s_pen[4], s_cnt[4];
    if (lane == 0) { s_ce[wave] = ce; s_pen[wave] = pen; s_cnt[wave] = cnt; }
    __syncthreads();
    if (tid == 0) {
        const float tce  = s_ce[0]  + s_ce[1]  + s_ce[2]  + s_ce[3];
        const float tpen = s_pen[0] + s_pen[1] + s_pen[2] + s_pen[3];
        const float tcnt = s_cnt[0] + s_cnt[1] + s_cnt[2] + s_cnt[3];
        const float mean_ce  = tce / (float)B;
        const float mean_pen = (tcnt > 0.0f) ? (tpen / tcnt) : 0.0f;
        out[0] = mean_ce + PEN_WEIGHT * mean_pen;
    }
}

extern "C" void kernel_launch(void* const* d_in, const int* in_sizes, int n_in,
                              void* d_out, int out_size, void* d_ws, size_t ws_size,
                              hipStream_t stream) {
    const float* predicts = (const float*)d_in[0];
    const int*   targets  = (const int*)d_in[1];
    const int B = in_sizes[1];                    // 1048576
    float* ws  = (float*)d_ws;
    float* out = (float*)d_out;

    const int nb = (B + ROWS_PER_BLOCK - 1) / ROWS_PER_BLOCK;   // 4096
    penalize_loss_main<<<nb, 256, 0, stream>>>(predicts, targets, ws, B, nb);
    finalize_kernel<<<1, 256, 0, stream>>>(ws, out, B, nb);
}